// Round 7
// baseline (780.424 us; speedup 1.0000x reference)
//
#include <hip/hip_runtime.h>
#include <math.h>

#define N_NODES 100000
#define N_EDGES 3200000
#define NEG 0.2f
#define NPB 128            // nodes per bucket
#define NB  782            // ceil(N_NODES / NPB)
#define CAP 4608           // staging capacity per bucket (mean 4096 + 8 sigma)
#define LOG2E 1.442695041f

typedef __attribute__((ext_vector_type(8))) short short8;
typedef __attribute__((ext_vector_type(4))) float f32x4;
typedef __attribute__((ext_vector_type(2))) float f32x2;

__device__ __forceinline__ float bflo(unsigned int u){
  union { unsigned int i; float f; } v; v.i = u << 16; return v.f;
}
__device__ __forceinline__ float bfhi(unsigned int u){
  union { unsigned int i; float f; } v; v.i = u & 0xffff0000u; return v.f;
}
__device__ __forceinline__ unsigned short f2bf(float f){
  union { float f; unsigned int i; } v; v.f = f;
  unsigned int r = v.i + 0x7fffu + ((v.i >> 16) & 1u);
  return (unsigned short)(r >> 16);
}
__device__ __forceinline__ unsigned int packbf(float lo, float hi){
  return (unsigned int)f2bf(lo) | ((unsigned int)f2bf(hi) << 16);
}
// 4x fp32 -> packed OCP e4m3 dword (HW cvt, gfx950)
__device__ __forceinline__ unsigned int pk_fp8x4(float a, float b, float c, float d){
  int v = 0;
  v = __builtin_amdgcn_cvt_pk_fp8_f32(a, b, v, false);
  v = __builtin_amdgcn_cvt_pk_fp8_f32(c, d, v, true);
  return (unsigned int)v;
}
__device__ __forceinline__ f32x2 unpk_fp8_lo(unsigned int v){
  return __builtin_amdgcn_cvt_pk_f32_fp8((int)v, false);
}
__device__ __forceinline__ f32x2 unpk_fp8_hi(unsigned int v){
  return __builtin_amdgcn_cvt_pk_f32_fp8((int)v, true);
}
// packed dual-f32 FMA: acc.lo += a.lo*w.lo ; acc.hi += a.hi*w.hi
__device__ __forceinline__ void pk_fma(f32x2 &acc, f32x2 a, f32x2 w){
  asm("v_pk_fma_f32 %0, %1, %2, %0" : "+v"(acc) : "v"(a), "v"(w));
}
// weight: exp2(leaky_relu(t)) with t pre-scaled by log2e; fmax form is exact
__device__ __forceinline__ float wexp(float t){
  return __builtin_amdgcn_exp2f(fmaxf(t, NEG * t));
}
// 16 fp8 bytes * w -> 8 packed-f32 accumulators
__device__ __forceinline__ void fma16(f32x2* acc, uint4 q, float w){
  f32x2 W; W[0]=w; W[1]=w;
  pk_fma(acc[0], unpk_fp8_lo(q.x), W);
  pk_fma(acc[1], unpk_fp8_hi(q.x), W);
  pk_fma(acc[2], unpk_fp8_lo(q.y), W);
  pk_fma(acc[3], unpk_fp8_hi(q.y), W);
  pk_fma(acc[4], unpk_fp8_lo(q.z), W);
  pk_fma(acc[5], unpk_fp8_hi(q.z), W);
  pk_fma(acc[6], unpk_fp8_lo(q.w), W);
  pk_fma(acc[7], unpk_fp8_hi(q.w), W);
}

// ---- fused prep: W1^T bf16, W2^T bf16, bucket cursor init ----
__global__ void k_prep(const float* __restrict__ W1, const float* __restrict__ W2,
                       unsigned short* __restrict__ W1t, unsigned short* __restrict__ W2t,
                       int* __restrict__ bcur){
  int i = blockIdx.x*256 + threadIdx.x;
  if (i < 65536){ int n = i >> 7, k = i & 127; W1t[i] = f2bf(W1[k*512 + n]); }
  else if (i < 98304){ int j = i - 65536; int n = j >> 9, k = j & 511; W2t[j] = f2bf(W2[k*64 + n]); }
  else if (i < 98304 + NB){ int b = i - 98304; bcur[b*16] = b*CAP; }
}

// ---- GEMM1 body (MFMA) + fused layer-1 scores; feat1 stored as fp8 e4m3 ----
__device__ void mm1_body(char* smraw, int mtile, int head,
    const float* __restrict__ A, const unsigned short* __restrict__ Bt,
    unsigned char* __restrict__ C8, int M,
    const float* __restrict__ al, const float* __restrict__ ar,
    float* __restrict__ el, float* __restrict__ er){
  unsigned short* sm = (unsigned short*)smraw;   // As 128x72 | Bs 128x72 (36.9 KB)
  unsigned short* As = sm;
  unsigned short* Bs = sm + 9216;
  const int t = threadIdx.x;
  const int w = t >> 6, l = t & 63;
  const int quad = l >> 4, l16 = l & 15;
  const int m0 = mtile * 128;
  const int moff = (w & 1) * 64, noff = (w >> 1) * 64;
  f32x4 acc[4][4];
  #pragma unroll
  for (int i=0;i<4;++i)
    #pragma unroll
    for (int j=0;j<4;++j){ acc[i][j][0]=0.f; acc[i][j][1]=0.f; acc[i][j][2]=0.f; acc[i][j][3]=0.f; }
  for (int kb = 0; kb < 2; ++kb){
    const int K0 = kb * 64;
    #pragma unroll
    for (int i=0;i<8;++i){              // A: 128x64 fp32 -> bf16 LDS
      int idx = t + i*256;
      int row = idx >> 4, c4 = (idx & 15) * 4;
      float4 v = make_float4(0.f,0.f,0.f,0.f);
      if (m0 + row < M) v = *(const float4*)(A + (size_t)(m0+row)*128 + K0 + c4);
      uint2 p; p.x = packbf(v.x, v.y); p.y = packbf(v.z, v.w);
      *(uint2*)(As + row*72 + c4) = p;
    }
    #pragma unroll
    for (int i=0;i<4;++i){              // B: 128x64 bf16 copy
      int idx = t + i*256;
      int row = idx >> 3, c8 = (idx & 7) * 8;
      *(uint4*)(Bs + row*72 + c8) =
        *(const uint4*)(Bt + (size_t)(head*128 + row)*128 + K0 + c8);
    }
    __syncthreads();
    #pragma unroll
    for (int ks = 0; ks < 2; ++ks){
      short8 af[4], bfr[4];
      #pragma unroll
      for (int mi=0; mi<4; ++mi)
        af[mi] = *(const short8*)(As + (moff + mi*16 + l16)*72 + ks*32 + quad*8);
      #pragma unroll
      for (int ni=0; ni<4; ++ni)
        bfr[ni] = *(const short8*)(Bs + (noff + ni*16 + l16)*72 + ks*32 + quad*8);
      #pragma unroll
      for (int mi=0; mi<4; ++mi)
        #pragma unroll
        for (int ni=0; ni<4; ++ni)
          acc[mi][ni] = __builtin_amdgcn_mfma_f32_16x16x32_bf16(af[mi], bfr[ni], acc[mi][ni], 0,0,0);
    }
    __syncthreads();
  }
  // epilogue: bf16 repack via LDS (exact values for scores), fp8 global store
  unsigned short* Cs = sm;                       // 128x136 bf16 (34.8 KB)
  #pragma unroll
  for (int mi=0; mi<4; ++mi)
    #pragma unroll
    for (int ni=0; ni<4; ++ni){
      int col = noff + ni*16 + l16;
      int rb  = moff + mi*16 + quad*4;
      #pragma unroll
      for (int r=0;r<4;++r) Cs[(rb+r)*136 + col] = f2bf(acc[mi][ni][r]);
    }
  __syncthreads();
  const int hcol = head * 128;
  #pragma unroll
  for (int i=0;i<8;++i){                // 128 rows x 128 cols, 8 fp8/thread/iter
    int e = t + i*256;
    int row = e >> 4, c8 = (e & 15) * 8;
    uint4 qb = *(const uint4*)(Cs + row*136 + c8);
    uint2 o;
    o.x = pk_fp8x4(bflo(qb.x), bfhi(qb.x), bflo(qb.y), bfhi(qb.y));
    o.y = pk_fp8x4(bflo(qb.z), bfhi(qb.z), bflo(qb.w), bfhi(qb.w));
    if (m0 + row < M)
      *(uint2*)(C8 + (size_t)(m0+row)*512 + hcol + c8) = o;
  }
  // fused scores: thread pair (t, t^1) covers one row (64 cols each)
  {
    int row = t >> 1, half = t & 1;
    const float* alp = al + head*128 + half*64;
    const float* arp = ar + head*128 + half*64;
    const unsigned short* cp = Cs + row*136 + half*64;
    float se = 0.f, sr = 0.f;
    #pragma unroll
    for (int i=0;i<8;++i){
      uint4 q = *(const uint4*)(cp + i*8);
      float4 a0 = *(const float4*)(alp + i*8), a1 = *(const float4*)(alp + i*8 + 4);
      float4 r0 = *(const float4*)(arp + i*8), r1 = *(const float4*)(arp + i*8 + 4);
      se += bflo(q.x)*a0.x + bfhi(q.x)*a0.y + bflo(q.y)*a0.z + bfhi(q.y)*a0.w
          + bflo(q.z)*a1.x + bfhi(q.z)*a1.y + bflo(q.w)*a1.z + bfhi(q.w)*a1.w;
      sr += bflo(q.x)*r0.x + bfhi(q.x)*r0.y + bflo(q.y)*r0.z + bfhi(q.y)*r0.w
          + bflo(q.z)*r1.x + bfhi(q.z)*r1.y + bflo(q.w)*r1.z + bfhi(q.w)*r1.w;
    }
    se += __shfl_xor(se, 1); sr += __shfl_xor(sr, 1);
    if (half == 0 && m0 + row < M){
      el[(m0+row)*4 + head] = se * LOG2E;   // pre-scale for exp2 weights
      er[(m0+row)*4 + head] = sr * LOG2E;
    }
  }
}

// ---- bucket scatter body (fixed-capacity staging) ----
__device__ void bucket_body(int eb, const int* __restrict__ src,
    const int* __restrict__ dst, int* __restrict__ bcur, int* __restrict__ staged){
  int e = eb*256 + threadIdx.x;
  if (e < N_EDGES){
    int d = dst[e];
    int b = d >> 7;
    int pos = atomicAdd(&bcur[b*16], 1);
    staged[pos] = (src[e] << 7) | (d & (NPB-1));
  }
}

// ---- per-bucket counting sort body; computes own prefix (no bscan pass) ----
__device__ void binsort_body(char* smraw, int b, const int* __restrict__ staged,
    const int* __restrict__ bcur, int* __restrict__ csr_src, int* __restrict__ indptr){
  int* hist = (int*)smraw;          // 128
  int* scan = hist + 128;           // 128
  int* lcur = scan + 128;           // 128
  int* red  = lcur + 128;           // 256
  const int t = threadIdx.x;
  const int st0 = b*CAP;
  const int cnt = bcur[b*16] - st0;
  // obase = sum of counts of buckets < b (block reduction over strided slices)
  int part = 0;
  for (int i = t; i < b; i += 256) part += bcur[i*16] - i*CAP;
  red[t] = part;
  if (t < NPB) hist[t] = 0;
  __syncthreads();
  for (int off = 128; off > 0; off >>= 1){
    if (t < off) red[t] += red[t + off];
    __syncthreads();
  }
  const int obase = red[0];
  for (int i = t; i < cnt; i += 256)
    atomicAdd(&hist[staged[st0 + i] & (NPB-1)], 1);
  __syncthreads();
  int v = (t < NPB) ? hist[t] : 0;
  if (t < NPB) scan[t] = v;
  __syncthreads();
  for (int off=1; off<NPB; off<<=1){
    int u = (t < NPB && t >= off) ? scan[t-off] : 0;
    __syncthreads();
    if (t < NPB) scan[t] += u;
    __syncthreads();
  }
  const int node0 = b * NPB;
  if (t < NPB){
    int ex = obase + scan[t] - v;    // global exclusive offset for node0+t
    lcur[t] = ex;
    if (node0 + t < N_NODES) indptr[node0 + t] = ex;
  }
  if (b == NB-1 && t == 0) indptr[N_NODES] = N_EDGES;
  __syncthreads();
  for (int i = t; i < cnt; i += 256){
    int pv = staged[st0 + i];
    int pos = atomicAdd(&lcur[pv & (NPB-1)], 1);
    csr_src[pos] = pv >> 7;
  }
}

// ---- fatA: mm1 heads 0-1 (1564 blocks) interleaved 1:8 with bucket (12500) ----
__global__ __launch_bounds__(256) void k_fatA(const float* __restrict__ x,
    const unsigned short* __restrict__ W1t, unsigned char* __restrict__ feat1,
    const float* __restrict__ al1, const float* __restrict__ ar1,
    float* __restrict__ el1, float* __restrict__ er1,
    const int* __restrict__ src, const int* __restrict__ dst,
    int* __restrict__ bcur, int* __restrict__ staged){
  __shared__ char smraw[36864];
  int b = blockIdx.x;
  int r = b % 9;
  if (r == 0){
    int id = b / 9;                       // 0..1563
    mm1_body(smraw, id % 782, id / 782, x, W1t, feat1, N_NODES, al1, ar1, el1, er1);
  } else {
    int id = (b/9)*8 + (r-1);             // 0..12511
    if (id < 12500) bucket_body(id, src, dst, bcur, staged);
  }
}

// ---- fatB: mm1 heads 2-3 (1564 blocks) interleaved 2:1 with binsort (782) ----
__global__ __launch_bounds__(256) void k_fatB(const float* __restrict__ x,
    const unsigned short* __restrict__ W1t, unsigned char* __restrict__ feat1,
    const float* __restrict__ al1, const float* __restrict__ ar1,
    float* __restrict__ el1, float* __restrict__ er1,
    const int* __restrict__ staged, const int* __restrict__ bcur,
    int* __restrict__ csr_src, int* __restrict__ indptr){
  __shared__ char smraw[36864];
  int b = blockIdx.x;
  int r = b % 3;
  if (r < 2){
    int id = (b/3)*2 + r;                 // 0..1563
    mm1_body(smraw, id % 782, 2 + id / 782, x, W1t, feat1, N_NODES, al1, ar1, el1, er1);
  } else {
    int id = b / 3;                       // 0..781
    binsort_body(smraw, id, staged, bcur, csr_src, indptr);
  }
}

// ---- GEMM2 (MFMA) + fused layer-2 scores ----
__global__ __launch_bounds__(256) void k_mm2(const unsigned short* __restrict__ A,
    const unsigned short* __restrict__ Bt,
    unsigned short* __restrict__ C, int M,
    const float* __restrict__ al, const float* __restrict__ ar,
    float* __restrict__ el, float* __restrict__ er){
  __shared__ unsigned short sm[13824];          // As 128x72 | Bs 64x72 (27.6 KB)
  unsigned short* As = sm;
  unsigned short* Bs = sm + 9216;
  const int t = threadIdx.x;
  const int w = t >> 6, l = t & 63;
  const int quad = l >> 4, l16 = l & 15;
  const int m0 = blockIdx.x * 128;
  const int moff = w * 32;
  f32x4 acc[2][4];
  #pragma unroll
  for (int i=0;i<2;++i)
    #pragma unroll
    for (int j=0;j<4;++j){ acc[i][j][0]=0.f; acc[i][j][1]=0.f; acc[i][j][2]=0.f; acc[i][j][3]=0.f; }
  for (int kb = 0; kb < 8; ++kb){
    const int K0 = kb * 64;
    #pragma unroll
    for (int i=0;i<4;++i){
      int idx = t + i*256;
      int row = idx >> 3, c8 = (idx & 7) * 8;
      uint4 v; v.x=0u; v.y=0u; v.z=0u; v.w=0u;
      if (m0 + row < M) v = *(const uint4*)(A + (size_t)(m0+row)*512 + K0 + c8);
      *(uint4*)(As + row*72 + c8) = v;
    }
    #pragma unroll
    for (int i=0;i<2;++i){
      int idx = t + i*256;
      int row = idx >> 3, c8 = (idx & 7) * 8;
      *(uint4*)(Bs + row*72 + c8) = *(const uint4*)(Bt + (size_t)row*512 + K0 + c8);
    }
    __syncthreads();
    #pragma unroll
    for (int ks = 0; ks < 2; ++ks){
      short8 af[2], bfr[4];
      #pragma unroll
      for (int mi=0; mi<2; ++mi)
        af[mi] = *(const short8*)(As + (moff + mi*16 + l16)*72 + ks*32 + quad*8);
      #pragma unroll
      for (int ni=0; ni<4; ++ni)
        bfr[ni] = *(const short8*)(Bs + (ni*16 + l16)*72 + ks*32 + quad*8);
      #pragma unroll
      for (int mi=0; mi<2; ++mi)
        #pragma unroll
        for (int ni=0; ni<4; ++ni)
          acc[mi][ni] = __builtin_amdgcn_mfma_f32_16x16x32_bf16(af[mi], bfr[ni], acc[mi][ni], 0,0,0);
    }
    __syncthreads();
  }
  unsigned short* Cs = sm;                       // 128x72 bf16
  #pragma unroll
  for (int mi=0; mi<2; ++mi)
    #pragma unroll
    for (int ni=0; ni<4; ++ni){
      int col = ni*16 + l16;
      int rb  = moff + mi*16 + quad*4;
      #pragma unroll
      for (int r=0;r<4;++r) Cs[(rb+r)*72 + col] = f2bf(acc[mi][ni][r]);
    }
  __syncthreads();
  #pragma unroll
  for (int i=0;i<4;++i){
    int e = t + i*256;
    int row = e >> 3, c8 = (e & 7) * 8;
    if (m0 + row < M)
      *(uint4*)(C + (size_t)(m0+row)*64 + c8) = *(const uint4*)(Cs + row*72 + c8);
  }
  // fused scores: thread pair covers one row (32 cols each)
  {
    int row = t >> 1, half = t & 1;
    const float* alp = al + half*32;
    const float* arp = ar + half*32;
    const unsigned short* cp = Cs + row*72 + half*32;
    float se = 0.f, sr = 0.f;
    #pragma unroll
    for (int i=0;i<4;++i){
      uint4 q = *(const uint4*)(cp + i*8);
      float4 a0 = *(const float4*)(alp + i*8), a1 = *(const float4*)(alp + i*8 + 4);
      float4 r0 = *(const float4*)(arp + i*8), r1 = *(const float4*)(arp + i*8 + 4);
      se += bflo(q.x)*a0.x + bfhi(q.x)*a0.y + bflo(q.y)*a0.z + bfhi(q.y)*a0.w
          + bflo(q.z)*a1.x + bfhi(q.z)*a1.y + bflo(q.w)*a1.z + bfhi(q.w)*a1.w;
      sr += bflo(q.x)*r0.x + bfhi(q.x)*r0.y + bflo(q.y)*r0.z + bfhi(q.y)*r0.w
          + bflo(q.z)*r1.x + bfhi(q.z)*r1.y + bflo(q.w)*r1.z + bfhi(q.w)*r1.w;
    }
    se += __shfl_xor(se, 1); sr += __shfl_xor(sr, 1);
    if (half == 0 && m0 + row < M){
      el[m0+row] = se * LOG2E;   // pre-scale for exp2 weights
      er[m0+row] = sr * LOG2E;
    }
  }
}

// ---- layer-1 aggregate + ELU: half-wave per edge (32 lanes x 16B = 512B row) ----
// 4 loads in flight cover 8 edges; halves combined once per node via shfl_xor(32).
__global__ __launch_bounds__(256) void k_agg1(const unsigned char* __restrict__ feat,
    const float* __restrict__ el, const float* __restrict__ er,
    const int* __restrict__ indptr, const int* __restrict__ csr_src,
    unsigned short* __restrict__ out){
  int wave = threadIdx.x >> 6, lane = threadIdx.x & 63;
  int n = blockIdx.x*4 + wave;
  if (n >= N_NODES) return;
  int p0 = indptr[n], p1 = indptr[n+1];
  const int half = lane >> 5, hl = lane & 31;
  const int hh = hl >> 3;                 // head = (hl*16)/128
  const unsigned d0 = hl * 16u;           // byte offset in 512B row
  const float myer = er[n*4 + hh];
  float ssum = 0.f;
  f32x2 acc[8];
  #pragma unroll
  for (int i=0;i<8;++i){ acc[i][0]=0.f; acc[i][1]=0.f; }
  int e = p0;
  for (; e + 7 < p1; e += 8){
    int s0 = csr_src[e + 0 + half];
    int s1 = csr_src[e + 2 + half];
    int s2 = csr_src[e + 4 + half];
    int s3 = csr_src[e + 6 + half];
    uint4 q0 = *(const uint4*)(feat + (((unsigned)s0) << 9) + d0);
    uint4 q1 = *(const uint4*)(feat + (((unsigned)s1) << 9) + d0);
    uint4 q2 = *(const uint4*)(feat + (((unsigned)s2) << 9) + d0);
    uint4 q3 = *(const uint4*)(feat + (((unsigned)s3) << 9) + d0);
    float t0 = el[(s0<<2) + hh] + myer;
    float t1 = el[(s1<<2) + hh] + myer;
    float t2 = el[(s2<<2) + hh] + myer;
    float t3 = el[(s3<<2) + hh] + myer;
    float w0 = wexp(t0), w1 = wexp(t1), w2 = wexp(t2), w3 = wexp(t3);
    ssum += (w0 + w1) + (w2 + w3);
    fma16(acc, q0, w0);
    fma16(acc, q1, w1);
    fma16(acc, q2, w2);
    fma16(acc, q3, w3);
  }
  for (; e < p1; e += 2){
    int idx = e + half;
    bool ok = idx < p1;
    int s = csr_src[ok ? idx : e];
    uint4 q = *(const uint4*)(feat + (((unsigned)s) << 9) + d0);
    float w = ok ? wexp(el[(s<<2) + hh] + myer) : 0.f;
    ssum += w;
    fma16(acc, q, w);
  }
  // combine the two halves (same dims, disjoint edge subsets)
  ssum += __shfl_xor(ssum, 32);
  float o16[16];
  #pragma unroll
  for (int i=0;i<8;++i){
    o16[2*i]   = acc[i][0] + __shfl_xor(acc[i][0], 32);
    o16[2*i+1] = acc[i][1] + __shfl_xor(acc[i][1], 32);
  }
  float inv = ssum > 0.f ? 1.f/ssum : 0.f;
  #pragma unroll
  for (int i=0;i<16;++i){
    float v = o16[i] * inv;
    o16[i] = v > 0.f ? v : __expf(v) - 1.f;   // fused ELU
  }
  if (half == 0){
    unsigned short* op = out + (size_t)n*512 + hl*16;
    uint4 oa, ob;
    oa.x = packbf(o16[0], o16[1]);  oa.y = packbf(o16[2], o16[3]);
    oa.z = packbf(o16[4], o16[5]);  oa.w = packbf(o16[6], o16[7]);
    ob.x = packbf(o16[8], o16[9]);  ob.y = packbf(o16[10],o16[11]);
    ob.z = packbf(o16[12],o16[13]); ob.w = packbf(o16[14],o16[15]);
    *(uint4*)op       = oa;
    *(uint4*)(op + 8) = ob;
  }
}

// ---- layer-2 aggregate: eighth-wave per edge, 2-edge unroll ----
__global__ __launch_bounds__(256) void k_agg2(const unsigned short* __restrict__ feat,
    const float* __restrict__ el, const float* __restrict__ er,
    const int* __restrict__ indptr, const int* __restrict__ csr_src,
    float* __restrict__ out){
  int wave = threadIdx.x >> 6, lane = threadIdx.x & 63;
  int n = blockIdx.x*4 + wave;
  if (n >= N_NODES) return;
  int p0 = indptr[n], p1 = indptr[n+1];
  float ern = er[n];
  int g = lane >> 3, ql = lane & 7;
  float s = 0.f;
  f32x2 acc[4];
  #pragma unroll
  for (int i=0;i<4;++i){ acc[i][0]=0.f; acc[i][1]=0.f; }
  int e = p0 + g;
  for (; e + 8 < p1; e += 16){
    int sa = csr_src[e], sb = csr_src[e+8];
    uint4 va = *(const uint4*)(feat + (size_t)sa*64 + ql*8);
    uint4 vb = *(const uint4*)(feat + (size_t)sb*64 + ql*8);
    float wa = wexp(el[sa] + ern);
    float wb = wexp(el[sb] + ern);
    s += wa + wb;
    f32x2 Wa; Wa[0]=wa; Wa[1]=wa;
    f32x2 Wb; Wb[0]=wb; Wb[1]=wb;
    f32x2 a;
    a[0]=bflo(va.x); a[1]=bfhi(va.x); pk_fma(acc[0], a, Wa);
    a[0]=bflo(va.y); a[1]=bfhi(va.y); pk_fma(acc[1], a, Wa);
    a[0]=bflo(va.z); a[1]=bfhi(va.z); pk_fma(acc[2], a, Wa);
    a[0]=bflo(va.w); a[1]=bfhi(va.w); pk_fma(acc[3], a, Wa);
    a[0]=bflo(vb.x); a[1]=bfhi(vb.x); pk_fma(acc[0], a, Wb);
    a[0]=bflo(vb.y); a[1]=bfhi(vb.y); pk_fma(acc[1], a, Wb);
    a[0]=bflo(vb.z); a[1]=bfhi(vb.z); pk_fma(acc[2], a, Wb);
    a[0]=bflo(vb.w); a[1]=bfhi(vb.w); pk_fma(acc[3], a, Wb);
  }
  for (; e < p1; e += 8){
    int si = csr_src[e];
    float w = wexp(el[si] + ern);
    uint4 v = *(const uint4*)(feat + (size_t)si*64 + ql*8);
    s += w;
    f32x2 W; W[0]=w; W[1]=w;
    f32x2 a;
    a[0]=bflo(v.x); a[1]=bfhi(v.x); pk_fma(acc[0], a, W);
    a[0]=bflo(v.y); a[1]=bfhi(v.y); pk_fma(acc[1], a, W);
    a[0]=bflo(v.z); a[1]=bfhi(v.z); pk_fma(acc[2], a, W);
    a[0]=bflo(v.w); a[1]=bfhi(v.w); pk_fma(acc[3], a, W);
  }
  #pragma unroll
  for (int m=8;m<64;m<<=1){
    s += __shfl_xor(s,m);
    #pragma unroll
    for (int i=0;i<4;++i){
      acc[i][0] += __shfl_xor(acc[i][0],m);
      acc[i][1] += __shfl_xor(acc[i][1],m);
    }
  }
  float inv = s > 0.f ? 1.f/s : 0.f;
  if (g == 0){
    float* op = out + (size_t)n*64 + ql*8;
    *(float4*)op     = make_float4(acc[0][0]*inv, acc[0][1]*inv, acc[1][0]*inv, acc[1][1]*inv);
    *(float4*)(op+4) = make_float4(acc[2][0]*inv, acc[2][1]*inv, acc[3][0]*inv, acc[3][1]*inv);
  }
}

extern "C" void kernel_launch(void* const* d_in, const int* in_sizes, int n_in,
                              void* d_out, int out_size, void* d_ws, size_t ws_size,
                              hipStream_t stream){
  const float* x   = (const float*)d_in[0];
  const float* W1  = (const float*)d_in[1];
  const float* al1 = (const float*)d_in[2];
  const float* ar1 = (const float*)d_in[3];
  const float* W2  = (const float*)d_in[4];
  const float* al2 = (const float*)d_in[5];
  const float* ar2 = (const float*)d_in[6];
  const int* src   = (const int*)d_in[7];
  const int* dst   = (const int*)d_in[8];
  float* out = (float*)d_out;

  char* ws = (char*)d_ws;
  size_t off = 0;
  auto alloc = [&](size_t bytes)->char*{
    char* p = ws + off; off += (bytes + 255) & ~(size_t)255; return p;
  };
  unsigned char*  feat1 = (unsigned char*)alloc((size_t)N_NODES*512);     // 51.2 MB fp8
  unsigned short* h1    = (unsigned short*)alloc((size_t)N_NODES*512*2);  // 102.4 MB
  unsigned short* feat2b = (unsigned short*)feat1;  // alias: feat1 dead after k_agg1
  unsigned short* W1t = (unsigned short*)alloc(512*128*2);
  unsigned short* W2t = (unsigned short*)alloc(64*512*2);
  float* el1 = (float*)alloc((size_t)N_NODES*4*4);
  float* er1 = (float*)alloc((size_t)N_NODES*4*4);
  float* el2 = el1;                           // alias: el1 dead after k_agg1
  float* er2 = er1;
  int* bcur    = (int*)alloc((size_t)NB*16*4);        // padded: 1 counter / 64B
  int* indptr  = (int*)alloc((size_t)(N_NODES+1)*4);
  int* staged  = (int*)alloc((size_t)NB*CAP*4);                           // 14.4 MB
  int* csr_src = (int*)alloc((size_t)N_EDGES*4);                          // 12.8 MB
  // total ~185 MB (< proven 222 MB footprint)

  dim3 b256(256);
  // prep: W1t, W2t, bucket cursors (one launch)
  k_prep<<<dim3(388), b256, 0, stream>>>(W1, W2, W1t, W2t, bcur);
  // fatA: mm1 heads 0-1 overlapped with bucket scatter (independent work)
  k_fatA<<<dim3(14076), b256, 0, stream>>>(x, W1t, feat1, al1, ar1, el1, er1,
                                           src, dst, bcur, staged);
  // fatB: mm1 heads 2-3 overlapped with per-bucket counting sort (bscan folded in)
  k_fatB<<<dim3(2346), b256, 0, stream>>>(x, W1t, feat1, al1, ar1, el1, er1,
                                          staged, bcur, csr_src, indptr);
  // layer-1 aggregate + ELU (single-pass, fp8 gather, half-wave per edge)
  k_agg1<<<dim3(25000), b256, 0, stream>>>(feat1, el1, er1, indptr, csr_src, h1);
  // layer 2 (MFMA) + fused scores
  k_mm2<<<dim3(782), b256, 0, stream>>>(h1, W2t, feat2b, N_NODES, al2, ar2, el2, er2);
  k_agg2<<<dim3(25000), b256, 0, stream>>>(feat2b, el2, er2, indptr, csr_src, out);
}

// Round 8
// 758.282 us; speedup vs baseline: 1.0292x; 1.0292x over previous
//
#include <hip/hip_runtime.h>
#include <math.h>

#define N_NODES 100000
#define N_EDGES 3200000
#define NEG 0.2f
#define NPB 128            // nodes per bucket
#define NB  782            // ceil(N_NODES / NPB)
#define CAP 4608           // staging capacity per bucket (mean 4096 + 8 sigma)
#define LOG2E 1.442695041f

typedef __attribute__((ext_vector_type(8))) short short8;
typedef __attribute__((ext_vector_type(4))) float f32x4;
typedef __attribute__((ext_vector_type(2))) float f32x2;

__device__ __forceinline__ float bflo(unsigned int u){
  union { unsigned int i; float f; } v; v.i = u << 16; return v.f;
}
__device__ __forceinline__ float bfhi(unsigned int u){
  union { unsigned int i; float f; } v; v.i = u & 0xffff0000u; return v.f;
}
__device__ __forceinline__ unsigned short f2bf(float f){
  union { float f; unsigned int i; } v; v.f = f;
  unsigned int r = v.i + 0x7fffu + ((v.i >> 16) & 1u);
  return (unsigned short)(r >> 16);
}
__device__ __forceinline__ unsigned int packbf(float lo, float hi){
  return (unsigned int)f2bf(lo) | ((unsigned int)f2bf(hi) << 16);
}
// 4x fp32 -> packed OCP e4m3 dword (HW cvt, gfx950)
__device__ __forceinline__ unsigned int pk_fp8x4(float a, float b, float c, float d){
  int v = 0;
  v = __builtin_amdgcn_cvt_pk_fp8_f32(a, b, v, false);
  v = __builtin_amdgcn_cvt_pk_fp8_f32(c, d, v, true);
  return (unsigned int)v;
}
__device__ __forceinline__ f32x2 unpk_fp8_lo(unsigned int v){
  return __builtin_amdgcn_cvt_pk_f32_fp8((int)v, false);
}
__device__ __forceinline__ f32x2 unpk_fp8_hi(unsigned int v){
  return __builtin_amdgcn_cvt_pk_f32_fp8((int)v, true);
}
// packed dual-f32 FMA: acc.lo += a.lo*w.lo ; acc.hi += a.hi*w.hi
__device__ __forceinline__ void pk_fma(f32x2 &acc, f32x2 a, f32x2 w){
  asm("v_pk_fma_f32 %0, %1, %2, %0" : "+v"(acc) : "v"(a), "v"(w));
}
// weight: exp2(leaky_relu(t)) with t pre-scaled by log2e; fmax form is exact
__device__ __forceinline__ float wexp(float t){
  return __builtin_amdgcn_exp2f(fmaxf(t, NEG * t));
}
// 16 fp8 bytes * w -> 8 packed-f32 accumulators
__device__ __forceinline__ void fma16(f32x2* acc, uint4 q, float w){
  f32x2 W; W[0]=w; W[1]=w;
  pk_fma(acc[0], unpk_fp8_lo(q.x), W);
  pk_fma(acc[1], unpk_fp8_hi(q.x), W);
  pk_fma(acc[2], unpk_fp8_lo(q.y), W);
  pk_fma(acc[3], unpk_fp8_hi(q.y), W);
  pk_fma(acc[4], unpk_fp8_lo(q.z), W);
  pk_fma(acc[5], unpk_fp8_hi(q.z), W);
  pk_fma(acc[6], unpk_fp8_lo(q.w), W);
  pk_fma(acc[7], unpk_fp8_hi(q.w), W);
}

// ---- fused prep: W1^T bf16, W2^T bf16, bucket cursor init ----
__global__ void k_prep(const float* __restrict__ W1, const float* __restrict__ W2,
                       unsigned short* __restrict__ W1t, unsigned short* __restrict__ W2t,
                       int* __restrict__ bcur){
  int i = blockIdx.x*256 + threadIdx.x;
  if (i < 65536){ int n = i >> 7, k = i & 127; W1t[i] = f2bf(W1[k*512 + n]); }
  else if (i < 98304){ int j = i - 65536; int n = j >> 9, k = j & 511; W2t[j] = f2bf(W2[k*64 + n]); }
  else if (i < 98304 + NB){ int b = i - 98304; bcur[b*16] = b*CAP; }
}

// ---- mm1 epilogue: bf16 repack via LDS (exact scores), fp8 store, scores ----
__device__ __forceinline__ void mm1_epi(unsigned short* Cs, const f32x4 (*acc)[4],
    int m0, int head, int moff, int noff, int M,
    unsigned char* __restrict__ C8,
    const float* __restrict__ al, const float* __restrict__ ar,
    float* __restrict__ el, float* __restrict__ er){
  const int t = threadIdx.x;
  const int l = t & 63;
  const int quad = l >> 4, l16 = l & 15;
  #pragma unroll
  for (int mi=0; mi<4; ++mi)
    #pragma unroll
    for (int ni=0; ni<4; ++ni){
      int col = noff + ni*16 + l16;
      int rb  = moff + mi*16 + quad*4;
      #pragma unroll
      for (int r=0;r<4;++r) Cs[(rb+r)*136 + col] = f2bf(acc[mi][ni][r]);
    }
  __syncthreads();
  const int hcol = head * 128;
  #pragma unroll
  for (int i=0;i<8;++i){                // 128 rows x 128 cols, 8 fp8/thread/iter
    int e = t + i*256;
    int row = e >> 4, c8 = (e & 15) * 8;
    uint4 qb = *(const uint4*)(Cs + row*136 + c8);
    uint2 o;
    o.x = pk_fp8x4(bflo(qb.x), bfhi(qb.x), bflo(qb.y), bfhi(qb.y));
    o.y = pk_fp8x4(bflo(qb.z), bfhi(qb.z), bflo(qb.w), bfhi(qb.w));
    if (m0 + row < M)
      *(uint2*)(C8 + (size_t)(m0+row)*512 + hcol + c8) = o;
  }
  // fused scores: thread pair (t, t^1) covers one row (64 cols each)
  {
    int row = t >> 1, half = t & 1;
    const float* alp = al + head*128 + half*64;
    const float* arp = ar + head*128 + half*64;
    const unsigned short* cp = Cs + row*136 + half*64;
    float se = 0.f, sr = 0.f;
    #pragma unroll
    for (int i=0;i<8;++i){
      uint4 q = *(const uint4*)(cp + i*8);
      float4 a0 = *(const float4*)(alp + i*8), a1 = *(const float4*)(alp + i*8 + 4);
      float4 r0 = *(const float4*)(arp + i*8), r1 = *(const float4*)(arp + i*8 + 4);
      se += bflo(q.x)*a0.x + bfhi(q.x)*a0.y + bflo(q.y)*a0.z + bfhi(q.y)*a0.w
          + bflo(q.z)*a1.x + bfhi(q.z)*a1.y + bflo(q.w)*a1.z + bfhi(q.w)*a1.w;
      sr += bflo(q.x)*r0.x + bfhi(q.x)*r0.y + bflo(q.y)*r0.z + bfhi(q.y)*r0.w
          + bflo(q.z)*r1.x + bfhi(q.z)*r1.y + bflo(q.w)*r1.z + bfhi(q.w)*r1.w;
    }
    se += __shfl_xor(se, 1); sr += __shfl_xor(sr, 1);
    if (half == 0 && m0 + row < M){
      el[(m0+row)*4 + head] = se * LOG2E;   // pre-scale for exp2 weights
      er[(m0+row)*4 + head] = sr * LOG2E;
    }
  }
}

// ---- GEMM1 (MFMA), 2 heads per block: x staged ONCE for both heads ----
__global__ __launch_bounds__(256) void k_mm1(const float* __restrict__ A,
    const unsigned short* __restrict__ Bt,
    unsigned char* __restrict__ C8, int M,
    const float* __restrict__ al, const float* __restrict__ ar,
    float* __restrict__ el, float* __restrict__ er){
  __shared__ unsigned short sm[36864];   // As0|As1|Bs0|Bs1, each 128x72 (73.7 KB)
  unsigned short* const As0 = sm;
  unsigned short* const As1 = sm + 9216;
  unsigned short* const Bs0 = sm + 18432;
  unsigned short* const Bs1 = sm + 27648;
  const int t = threadIdx.x;
  const int w = t >> 6, l = t & 63;
  const int quad = l >> 4, l16 = l & 15;
  const int m0 = blockIdx.x * 128;
  const int h0 = blockIdx.y * 2;            // heads h0, h0+1
  const int moff = (w & 1) * 64, noff = (w >> 1) * 64;
  f32x4 accA[4][4], accB[4][4];
  #pragma unroll
  for (int i=0;i<4;++i)
    #pragma unroll
    for (int j=0;j<4;++j){
      accA[i][j][0]=0.f; accA[i][j][1]=0.f; accA[i][j][2]=0.f; accA[i][j][3]=0.f;
      accB[i][j][0]=0.f; accB[i][j][1]=0.f; accB[i][j][2]=0.f; accB[i][j][3]=0.f;
    }
  // A: both K halves staged once (x read 1x per block instead of 1x per head)
  #pragma unroll
  for (int kb=0; kb<2; ++kb){
    unsigned short* As = kb ? As1 : As0;
    #pragma unroll
    for (int i=0;i<8;++i){
      int idx = t + i*256;
      int row = idx >> 4, c4 = (idx & 15) * 4;
      float4 v = make_float4(0.f,0.f,0.f,0.f);
      if (m0 + row < M) v = *(const float4*)(A + (size_t)(m0+row)*128 + kb*64 + c4);
      uint2 p; p.x = packbf(v.x, v.y); p.y = packbf(v.z, v.w);
      *(uint2*)(As + row*72 + c4) = p;
    }
  }
  // B: head h0, both K halves
  #pragma unroll
  for (int kb=0; kb<2; ++kb){
    unsigned short* Bs = kb ? Bs1 : Bs0;
    #pragma unroll
    for (int i=0;i<4;++i){
      int idx = t + i*256;
      int row = idx >> 3, c8 = (idx & 7) * 8;
      *(uint4*)(Bs + row*72 + c8) =
        *(const uint4*)(Bt + (size_t)(h0*128 + row)*128 + kb*64 + c8);
    }
  }
  __syncthreads();
  // MFMA head h0
  #pragma unroll
  for (int kb=0; kb<2; ++kb){
    const unsigned short* As = kb ? As1 : As0;
    const unsigned short* Bs = kb ? Bs1 : Bs0;
    #pragma unroll
    for (int ks = 0; ks < 2; ++ks){
      short8 af[4], bfr[4];
      #pragma unroll
      for (int mi=0; mi<4; ++mi)
        af[mi] = *(const short8*)(As + (moff + mi*16 + l16)*72 + ks*32 + quad*8);
      #pragma unroll
      for (int ni=0; ni<4; ++ni)
        bfr[ni] = *(const short8*)(Bs + (noff + ni*16 + l16)*72 + ks*32 + quad*8);
      #pragma unroll
      for (int mi=0; mi<4; ++mi)
        #pragma unroll
        for (int ni=0; ni<4; ++ni)
          accA[mi][ni] = __builtin_amdgcn_mfma_f32_16x16x32_bf16(af[mi], bfr[ni], accA[mi][ni], 0,0,0);
    }
  }
  __syncthreads();
  // B: head h0+1 (reuse Bs buffers)
  #pragma unroll
  for (int kb=0; kb<2; ++kb){
    unsigned short* Bs = kb ? Bs1 : Bs0;
    #pragma unroll
    for (int i=0;i<4;++i){
      int idx = t + i*256;
      int row = idx >> 3, c8 = (idx & 7) * 8;
      *(uint4*)(Bs + row*72 + c8) =
        *(const uint4*)(Bt + (size_t)((h0+1)*128 + row)*128 + kb*64 + c8);
    }
  }
  __syncthreads();
  // MFMA head h0+1
  #pragma unroll
  for (int kb=0; kb<2; ++kb){
    const unsigned short* As = kb ? As1 : As0;
    const unsigned short* Bs = kb ? Bs1 : Bs0;
    #pragma unroll
    for (int ks = 0; ks < 2; ++ks){
      short8 af[4], bfr[4];
      #pragma unroll
      for (int mi=0; mi<4; ++mi)
        af[mi] = *(const short8*)(As + (moff + mi*16 + l16)*72 + ks*32 + quad*8);
      #pragma unroll
      for (int ni=0; ni<4; ++ni)
        bfr[ni] = *(const short8*)(Bs + (ni*16 + l16 + noff)*72 + ks*32 + quad*8);
      #pragma unroll
      for (int mi=0; mi<4; ++mi)
        #pragma unroll
        for (int ni=0; ni<4; ++ni)
          accB[mi][ni] = __builtin_amdgcn_mfma_f32_16x16x32_bf16(af[mi], bfr[ni], accB[mi][ni], 0,0,0);
    }
  }
  __syncthreads();   // all As/Bs reads done; As region becomes Cs scratch
  mm1_epi(sm, accA, m0, h0,   moff, noff, M, C8, al, ar, el, er);
  __syncthreads();   // Cs reads of head h0 done before overwrite
  mm1_epi(sm, accB, m0, h0+1, moff, noff, M, C8, al, ar, el, er);
}

// ---- GEMM2 (MFMA) + fused layer-2 scores ----
__global__ __launch_bounds__(256) void k_mm2(const unsigned short* __restrict__ A,
    const unsigned short* __restrict__ Bt,
    unsigned short* __restrict__ C, int M,
    const float* __restrict__ al, const float* __restrict__ ar,
    float* __restrict__ el, float* __restrict__ er){
  __shared__ unsigned short sm[13824];          // As 128x72 | Bs 64x72 (27.6 KB)
  unsigned short* As = sm;
  unsigned short* Bs = sm + 9216;
  const int t = threadIdx.x;
  const int w = t >> 6, l = t & 63;
  const int quad = l >> 4, l16 = l & 15;
  const int m0 = blockIdx.x * 128;
  const int moff = w * 32;
  f32x4 acc[2][4];
  #pragma unroll
  for (int i=0;i<2;++i)
    #pragma unroll
    for (int j=0;j<4;++j){ acc[i][j][0]=0.f; acc[i][j][1]=0.f; acc[i][j][2]=0.f; acc[i][j][3]=0.f; }
  for (int kb = 0; kb < 8; ++kb){
    const int K0 = kb * 64;
    #pragma unroll
    for (int i=0;i<4;++i){
      int idx = t + i*256;
      int row = idx >> 3, c8 = (idx & 7) * 8;
      uint4 v; v.x=0u; v.y=0u; v.z=0u; v.w=0u;
      if (m0 + row < M) v = *(const uint4*)(A + (size_t)(m0+row)*512 + K0 + c8);
      *(uint4*)(As + row*72 + c8) = v;
    }
    #pragma unroll
    for (int i=0;i<2;++i){
      int idx = t + i*256;
      int row = idx >> 3, c8 = (idx & 7) * 8;
      *(uint4*)(Bs + row*72 + c8) = *(const uint4*)(Bt + (size_t)row*512 + K0 + c8);
    }
    __syncthreads();
    #pragma unroll
    for (int ks = 0; ks < 2; ++ks){
      short8 af[2], bfr[4];
      #pragma unroll
      for (int mi=0; mi<2; ++mi)
        af[mi] = *(const short8*)(As + (moff + mi*16 + l16)*72 + ks*32 + quad*8);
      #pragma unroll
      for (int ni=0; ni<4; ++ni)
        bfr[ni] = *(const short8*)(Bs + (ni*16 + l16)*72 + ks*32 + quad*8);
      #pragma unroll
      for (int mi=0; mi<2; ++mi)
        #pragma unroll
        for (int ni=0; ni<4; ++ni)
          acc[mi][ni] = __builtin_amdgcn_mfma_f32_16x16x32_bf16(af[mi], bfr[ni], acc[mi][ni], 0,0,0);
    }
    __syncthreads();
  }
  unsigned short* Cs = sm;                       // 128x72 bf16
  #pragma unroll
  for (int mi=0; mi<2; ++mi)
    #pragma unroll
    for (int ni=0; ni<4; ++ni){
      int col = ni*16 + l16;
      int rb  = moff + mi*16 + quad*4;
      #pragma unroll
      for (int r=0;r<4;++r) Cs[(rb+r)*72 + col] = f2bf(acc[mi][ni][r]);
    }
  __syncthreads();
  #pragma unroll
  for (int i=0;i<4;++i){
    int e = t + i*256;
    int row = e >> 3, c8 = (e & 7) * 8;
    if (m0 + row < M)
      *(uint4*)(C + (size_t)(m0+row)*64 + c8) = *(const uint4*)(Cs + row*72 + c8);
  }
  // fused scores: thread pair covers one row (32 cols each)
  {
    int row = t >> 1, half = t & 1;
    const float* alp = al + half*32;
    const float* arp = ar + half*32;
    const unsigned short* cp = Cs + row*72 + half*32;
    float se = 0.f, sr = 0.f;
    #pragma unroll
    for (int i=0;i<4;++i){
      uint4 q = *(const uint4*)(cp + i*8);
      float4 a0 = *(const float4*)(alp + i*8), a1 = *(const float4*)(alp + i*8 + 4);
      float4 r0 = *(const float4*)(arp + i*8), r1 = *(const float4*)(arp + i*8 + 4);
      se += bflo(q.x)*a0.x + bfhi(q.x)*a0.y + bflo(q.y)*a0.z + bfhi(q.y)*a0.w
          + bflo(q.z)*a1.x + bfhi(q.z)*a1.y + bflo(q.w)*a1.z + bfhi(q.w)*a1.w;
      sr += bflo(q.x)*r0.x + bfhi(q.x)*r0.y + bflo(q.y)*r0.z + bfhi(q.y)*r0.w
          + bflo(q.z)*r1.x + bfhi(q.z)*r1.y + bflo(q.w)*r1.z + bfhi(q.w)*r1.w;
    }
    se += __shfl_xor(se, 1); sr += __shfl_xor(sr, 1);
    if (half == 0 && m0 + row < M){
      el[m0+row] = se * LOG2E;   // pre-scale for exp2 weights
      er[m0+row] = sr * LOG2E;
    }
  }
}

// ---- bucketed CSR build (fixed-capacity staging; no count pass) ----
__global__ void k_bucket(const int* __restrict__ src, const int* __restrict__ dst,
                         int* __restrict__ bcur, int* __restrict__ staged){
  int e = blockIdx.x*blockDim.x + threadIdx.x;
  if (e < N_EDGES){
    int d = dst[e];
    int b = d >> 7;
    int pos = atomicAdd(&bcur[b*16], 1);
    staged[pos] = (src[e] << 7) | (d & (NPB-1));
  }
}
__global__ __launch_bounds__(1024) void k_bscan(const int* __restrict__ bcur,
    int* __restrict__ bbase){
  __shared__ int lds[1024];
  int t = threadIdx.x;
  int v = (t < NB) ? (bcur[t*16] - t*CAP) : 0;
  lds[t] = v; __syncthreads();
  for (int off=1; off<1024; off<<=1){
    int u = (t>=off)? lds[t-off] : 0;
    __syncthreads();
    lds[t] += u;
    __syncthreads();
  }
  if (t < NB) bbase[t] = lds[t] - v;   // exclusive prefix
  if (t == 0) bbase[NB] = N_EDGES;
}
__global__ __launch_bounds__(256) void k_binsort(const int* __restrict__ staged,
    const int* __restrict__ bcur, const int* __restrict__ bbase,
    int* __restrict__ csr_src, int* __restrict__ indptr){
  __shared__ int hist[NPB];
  __shared__ int scan[NPB];
  __shared__ int lcur[NPB];
  const int b = blockIdx.x, t = threadIdx.x;
  const int st0 = b*CAP;
  const int cnt = bcur[b*16] - st0;
  const int obase = bbase[b];
  if (t < NPB) hist[t] = 0;
  __syncthreads();
  for (int i = t; i < cnt; i += 256)
    atomicAdd(&hist[staged[st0 + i] & (NPB-1)], 1);
  __syncthreads();
  int v = (t < NPB) ? hist[t] : 0;
  if (t < NPB) scan[t] = v;
  __syncthreads();
  for (int off=1; off<NPB; off<<=1){
    int u = (t < NPB && t >= off) ? scan[t-off] : 0;
    __syncthreads();
    if (t < NPB) scan[t] += u;
    __syncthreads();
  }
  const int node0 = b * NPB;
  if (t < NPB){
    int ex = obase + scan[t] - v;    // global exclusive offset for node0+t
    lcur[t] = ex;
    if (node0 + t < N_NODES) indptr[node0 + t] = ex;
  }
  if (b == NB-1 && t == 0) indptr[N_NODES] = N_EDGES;
  __syncthreads();
  for (int i = t; i < cnt; i += 256){
    int pv = staged[st0 + i];
    int pos = atomicAdd(&lcur[pv & (NPB-1)], 1);
    csr_src[pos] = pv >> 7;
  }
}

// ---- layer-1 aggregate + ELU: half-wave per edge (32 lanes x 16B = 512B row) ----
// 4 loads in flight cover 8 edges; halves combined once per node via shfl_xor(32).
__global__ __launch_bounds__(256) void k_agg1(const unsigned char* __restrict__ feat,
    const float* __restrict__ el, const float* __restrict__ er,
    const int* __restrict__ indptr, const int* __restrict__ csr_src,
    unsigned short* __restrict__ out){
  int wave = threadIdx.x >> 6, lane = threadIdx.x & 63;
  int n = blockIdx.x*4 + wave;
  if (n >= N_NODES) return;
  int p0 = indptr[n], p1 = indptr[n+1];
  const int half = lane >> 5, hl = lane & 31;
  const int hh = hl >> 3;                 // head = (hl*16)/128
  const unsigned d0 = hl * 16u;           // byte offset in 512B row
  const float myer = er[n*4 + hh];
  float ssum = 0.f;
  f32x2 acc[8];
  #pragma unroll
  for (int i=0;i<8;++i){ acc[i][0]=0.f; acc[i][1]=0.f; }
  int e = p0;
  for (; e + 7 < p1; e += 8){
    int s0 = csr_src[e + 0 + half];
    int s1 = csr_src[e + 2 + half];
    int s2 = csr_src[e + 4 + half];
    int s3 = csr_src[e + 6 + half];
    uint4 q0 = *(const uint4*)(feat + (((unsigned)s0) << 9) + d0);
    uint4 q1 = *(const uint4*)(feat + (((unsigned)s1) << 9) + d0);
    uint4 q2 = *(const uint4*)(feat + (((unsigned)s2) << 9) + d0);
    uint4 q3 = *(const uint4*)(feat + (((unsigned)s3) << 9) + d0);
    float t0 = el[(s0<<2) + hh] + myer;
    float t1 = el[(s1<<2) + hh] + myer;
    float t2 = el[(s2<<2) + hh] + myer;
    float t3 = el[(s3<<2) + hh] + myer;
    float w0 = wexp(t0), w1 = wexp(t1), w2 = wexp(t2), w3 = wexp(t3);
    ssum += (w0 + w1) + (w2 + w3);
    fma16(acc, q0, w0);
    fma16(acc, q1, w1);
    fma16(acc, q2, w2);
    fma16(acc, q3, w3);
  }
  for (; e < p1; e += 2){
    int idx = e + half;
    bool ok = idx < p1;
    int s = csr_src[ok ? idx : e];
    uint4 q = *(const uint4*)(feat + (((unsigned)s) << 9) + d0);
    float w = ok ? wexp(el[(s<<2) + hh] + myer) : 0.f;
    ssum += w;
    fma16(acc, q, w);
  }
  // combine the two halves (same dims, disjoint edge subsets)
  ssum += __shfl_xor(ssum, 32);
  float o16[16];
  #pragma unroll
  for (int i=0;i<8;++i){
    o16[2*i]   = acc[i][0] + __shfl_xor(acc[i][0], 32);
    o16[2*i+1] = acc[i][1] + __shfl_xor(acc[i][1], 32);
  }
  float inv = ssum > 0.f ? 1.f/ssum : 0.f;
  #pragma unroll
  for (int i=0;i<16;++i){
    float v = o16[i] * inv;
    o16[i] = v > 0.f ? v : __expf(v) - 1.f;   // fused ELU
  }
  if (half == 0){
    unsigned short* op = out + (size_t)n*512 + hl*16;
    uint4 oa, ob;
    oa.x = packbf(o16[0], o16[1]);  oa.y = packbf(o16[2], o16[3]);
    oa.z = packbf(o16[4], o16[5]);  oa.w = packbf(o16[6], o16[7]);
    ob.x = packbf(o16[8], o16[9]);  ob.y = packbf(o16[10],o16[11]);
    ob.z = packbf(o16[12],o16[13]); ob.w = packbf(o16[14],o16[15]);
    *(uint4*)op       = oa;
    *(uint4*)(op + 8) = ob;
  }
}

// ---- layer-2 aggregate: eighth-wave per edge, 2-edge unroll ----
__global__ __launch_bounds__(256) void k_agg2(const unsigned short* __restrict__ feat,
    const float* __restrict__ el, const float* __restrict__ er,
    const int* __restrict__ indptr, const int* __restrict__ csr_src,
    float* __restrict__ out){
  int wave = threadIdx.x >> 6, lane = threadIdx.x & 63;
  int n = blockIdx.x*4 + wave;
  if (n >= N_NODES) return;
  int p0 = indptr[n], p1 = indptr[n+1];
  float ern = er[n];
  int g = lane >> 3, ql = lane & 7;
  float s = 0.f;
  f32x2 acc[4];
  #pragma unroll
  for (int i=0;i<4;++i){ acc[i][0]=0.f; acc[i][1]=0.f; }
  int e = p0 + g;
  for (; e + 8 < p1; e += 16){
    int sa = csr_src[e], sb = csr_src[e+8];
    uint4 va = *(const uint4*)(feat + (size_t)sa*64 + ql*8);
    uint4 vb = *(const uint4*)(feat + (size_t)sb*64 + ql*8);
    float wa = wexp(el[sa] + ern);
    float wb = wexp(el[sb] + ern);
    s += wa + wb;
    f32x2 Wa; Wa[0]=wa; Wa[1]=wa;
    f32x2 Wb; Wb[0]=wb; Wb[1]=wb;
    f32x2 a;
    a[0]=bflo(va.x); a[1]=bfhi(va.x); pk_fma(acc[0], a, Wa);
    a[0]=bflo(va.y); a[1]=bfhi(va.y); pk_fma(acc[1], a, Wa);
    a[0]=bflo(va.z); a[1]=bfhi(va.z); pk_fma(acc[2], a, Wa);
    a[0]=bflo(va.w); a[1]=bfhi(va.w); pk_fma(acc[3], a, Wa);
    a[0]=bflo(vb.x); a[1]=bfhi(vb.x); pk_fma(acc[0], a, Wb);
    a[0]=bflo(vb.y); a[1]=bfhi(vb.y); pk_fma(acc[1], a, Wb);
    a[0]=bflo(vb.z); a[1]=bfhi(vb.z); pk_fma(acc[2], a, Wb);
    a[0]=bflo(vb.w); a[1]=bfhi(vb.w); pk_fma(acc[3], a, Wb);
  }
  for (; e < p1; e += 8){
    int si = csr_src[e];
    float w = wexp(el[si] + ern);
    uint4 v = *(const uint4*)(feat + (size_t)si*64 + ql*8);
    s += w;
    f32x2 W; W[0]=w; W[1]=w;
    f32x2 a;
    a[0]=bflo(v.x); a[1]=bfhi(v.x); pk_fma(acc[0], a, W);
    a[0]=bflo(v.y); a[1]=bfhi(v.y); pk_fma(acc[1], a, W);
    a[0]=bflo(v.z); a[1]=bfhi(v.z); pk_fma(acc[2], a, W);
    a[0]=bflo(v.w); a[1]=bfhi(v.w); pk_fma(acc[3], a, W);
  }
  #pragma unroll
  for (int m=8;m<64;m<<=1){
    s += __shfl_xor(s,m);
    #pragma unroll
    for (int i=0;i<4;++i){
      acc[i][0] += __shfl_xor(acc[i][0],m);
      acc[i][1] += __shfl_xor(acc[i][1],m);
    }
  }
  float inv = s > 0.f ? 1.f/s : 0.f;
  if (g == 0){
    float* op = out + (size_t)n*64 + ql*8;
    *(float4*)op     = make_float4(acc[0][0]*inv, acc[0][1]*inv, acc[1][0]*inv, acc[1][1]*inv);
    *(float4*)(op+4) = make_float4(acc[2][0]*inv, acc[2][1]*inv, acc[3][0]*inv, acc[3][1]*inv);
  }
}

extern "C" void kernel_launch(void* const* d_in, const int* in_sizes, int n_in,
                              void* d_out, int out_size, void* d_ws, size_t ws_size,
                              hipStream_t stream){
  const float* x   = (const float*)d_in[0];
  const float* W1  = (const float*)d_in[1];
  const float* al1 = (const float*)d_in[2];
  const float* ar1 = (const float*)d_in[3];
  const float* W2  = (const float*)d_in[4];
  const float* al2 = (const float*)d_in[5];
  const float* ar2 = (const float*)d_in[6];
  const int* src   = (const int*)d_in[7];
  const int* dst   = (const int*)d_in[8];
  float* out = (float*)d_out;

  char* ws = (char*)d_ws;
  size_t off = 0;
  auto alloc = [&](size_t bytes)->char*{
    char* p = ws + off; off += (bytes + 255) & ~(size_t)255; return p;
  };
  unsigned char*  feat1 = (unsigned char*)alloc((size_t)N_NODES*512);     // 51.2 MB fp8
  unsigned short* h1    = (unsigned short*)alloc((size_t)N_NODES*512*2);  // 102.4 MB
  unsigned short* feat2b = (unsigned short*)feat1;  // alias: feat1 dead after k_agg1
  unsigned short* W1t = (unsigned short*)alloc(512*128*2);
  unsigned short* W2t = (unsigned short*)alloc(64*512*2);
  float* el1 = (float*)alloc((size_t)N_NODES*4*4);
  float* er1 = (float*)alloc((size_t)N_NODES*4*4);
  float* el2 = el1;                           // alias: el1 dead after k_agg1
  float* er2 = er1;
  int* bcur    = (int*)alloc((size_t)NB*16*4);        // padded: 1 counter / 64B
  int* bbase   = (int*)alloc((size_t)(NB+1)*4);
  int* indptr  = (int*)alloc((size_t)(N_NODES+1)*4);
  int* staged  = (int*)alloc((size_t)NB*CAP*4);                           // 14.4 MB
  int* csr_src = (int*)alloc((size_t)N_EDGES*4);                          // 12.8 MB
  // total ~185 MB (< proven 222 MB footprint)

  dim3 b256(256);
  // prep: W1t, W2t, bucket cursors (one launch)
  k_prep<<<dim3(388), b256, 0, stream>>>(W1, W2, W1t, W2t, bcur);
  // layer 1 projection (MFMA, 2 heads/block) + fused scores; feat1 -> fp8
  k_mm1<<<dim3(782, 2), b256, 0, stream>>>(x, W1t, feat1, N_NODES, al1, ar1, el1, er1);
  // bucketed dst-CSR: scatter into fixed-capacity buckets -> scan -> per-bucket sort
  k_bucket<<<dim3((N_EDGES+255)/256), b256, 0, stream>>>(src, dst, bcur, staged);
  k_bscan<<<dim3(1), dim3(1024), 0, stream>>>(bcur, bbase);
  k_binsort<<<dim3(NB), b256, 0, stream>>>(staged, bcur, bbase, csr_src, indptr);
  // layer-1 aggregate + ELU (single-pass, fp8 gather, half-wave per edge)
  k_agg1<<<dim3(25000), b256, 0, stream>>>(feat1, el1, er1, indptr, csr_src, h1);
  // layer 2 (MFMA) + fused scores
  k_mm2<<<dim3(782), b256, 0, stream>>>(h1, W2t, feat2b, N_NODES, al2, ar2, el2, er2);
  k_agg2<<<dim3(25000), b256, 0, stream>>>(feat2b, el2, er2, indptr, csr_src, out);
}

// Round 9
// 680.827 us; speedup vs baseline: 1.1463x; 1.1138x over previous
//
#include <hip/hip_runtime.h>
#include <math.h>

#define N_NODES 100000
#define N_EDGES 3200000
#define NEG 0.2f
#define NPB 128            // nodes per bucket
#define NB  782            // ceil(N_NODES / NPB)
#define CAP 4608           // staging capacity per bucket (mean 4096 + 8 sigma)
#define LOG2E 1.442695041f

typedef __attribute__((ext_vector_type(8))) short short8;
typedef __attribute__((ext_vector_type(4))) float f32x4;
typedef __attribute__((ext_vector_type(2))) float f32x2;

__device__ __forceinline__ float bflo(unsigned int u){
  union { unsigned int i; float f; } v; v.i = u << 16; return v.f;
}
__device__ __forceinline__ float bfhi(unsigned int u){
  union { unsigned int i; float f; } v; v.i = u & 0xffff0000u; return v.f;
}
__device__ __forceinline__ unsigned short f2bf(float f){
  union { float f; unsigned int i; } v; v.f = f;
  unsigned int r = v.i + 0x7fffu + ((v.i >> 16) & 1u);
  return (unsigned short)(r >> 16);
}
__device__ __forceinline__ unsigned int packbf(float lo, float hi){
  return (unsigned int)f2bf(lo) | ((unsigned int)f2bf(hi) << 16);
}
// packed dual-f32 FMA: acc.lo += a.lo*w.lo ; acc.hi += a.hi*w.hi
__device__ __forceinline__ void pk_fma(f32x2 &acc, f32x2 a, f32x2 w){
  asm("v_pk_fma_f32 %0, %1, %2, %0" : "+v"(acc) : "v"(a), "v"(w));
}
// weight: exp2(leaky_relu(t)) with t pre-scaled by log2e; fmax form is exact
__device__ __forceinline__ float wexp(float t){
  return __builtin_amdgcn_exp2f(fmaxf(t, NEG * t));
}
__device__ __forceinline__ f32x4 wexp4(f32x4 t){
  f32x4 r; r[0]=wexp(t[0]); r[1]=wexp(t[1]); r[2]=wexp(t[2]); r[3]=wexp(t[3]);
  return r;
}
// 8 bf16 dims of one edge's x-row, weighted into 4 per-head accumulators
__device__ __forceinline__ void fma_x8(f32x2 (*acc)[4], uint4 q, f32x4 w){
  f32x2 p0,p1,p2,p3;
  p0[0]=bflo(q.x); p0[1]=bfhi(q.x);
  p1[0]=bflo(q.y); p1[1]=bfhi(q.y);
  p2[0]=bflo(q.z); p2[1]=bfhi(q.z);
  p3[0]=bflo(q.w); p3[1]=bfhi(q.w);
  #pragma unroll
  for (int h=0;h<4;++h){
    f32x2 W; W[0]=w[h]; W[1]=w[h];
    pk_fma(acc[h][0], p0, W);
    pk_fma(acc[h][1], p1, W);
    pk_fma(acc[h][2], p2, W);
    pk_fma(acc[h][3], p3, W);
  }
}

// ---- prep: W1t, W2t, bucket cursors, score vectors val=W1*al / var=W1*ar ----
__global__ void k_prep(const float* __restrict__ W1, const float* __restrict__ W2,
                       const float* __restrict__ al1, const float* __restrict__ ar1,
                       unsigned short* __restrict__ W1t, unsigned short* __restrict__ W2t,
                       int* __restrict__ bcur, float* __restrict__ val,
                       float* __restrict__ var){
  int i = blockIdx.x*256 + threadIdx.x;
  if (i < 65536){ int n = i >> 7, k = i & 127; W1t[i] = f2bf(W1[k*512 + n]); }
  else if (i < 98304){ int j = i - 65536; int n = j >> 9, k = j & 511; W2t[j] = f2bf(W2[k*64 + n]); }
  else if (i < 98304 + NB){ int b = i - 98304; bcur[b*16] = b*CAP; }
  else if (i >= 99328 && i < 99840){
    int j = i - 99328; int k = j >> 2, h = j & 3;
    float s = 0.f;
    for (int d=0; d<128; ++d) s += W1[k*512 + h*128 + d] * al1[h*128 + d];
    val[j] = s;
  } else if (i >= 99840 && i < 100352){
    int j = i - 99840; int k = j >> 2, h = j & 3;
    float s = 0.f;
    for (int d=0; d<128; ++d) s += W1[k*512 + h*128 + d] * ar1[h*128 + d];
    var[j] = s;
  }
}

// ---- xcvt: x -> bf16 xb, plus layer-1 scores el/er = x . (val|var) ----
// quarter-wave per node: 16 lanes x 8 dims.
__global__ __launch_bounds__(256) void k_xcvt(const float* __restrict__ x,
    const float* __restrict__ val, const float* __restrict__ var,
    unsigned short* __restrict__ xb, float* __restrict__ el, float* __restrict__ er){
  int wave = threadIdx.x >> 6, lane = threadIdx.x & 63;
  int q = lane >> 4, ql = lane & 15;
  int n = (blockIdx.x*4 + wave)*4 + q;           // grid exact: 6250*16 = 100000
  f32x4 valr[8], varr[8];
  #pragma unroll
  for (int j=0;j<8;++j){
    valr[j] = *(const f32x4*)(val + (ql*8+j)*4);
    varr[j] = *(const f32x4*)(var + (ql*8+j)*4);
  }
  const float* xp = x + (size_t)n*128 + ql*8;
  float4 xa = *(const float4*)xp;
  float4 xc = *(const float4*)(xp + 4);
  uint4 o; o.x = packbf(xa.x,xa.y); o.y = packbf(xa.z,xa.w);
  o.z = packbf(xc.x,xc.y); o.w = packbf(xc.z,xc.w);
  *(uint4*)(xb + (size_t)n*128 + ql*8) = o;
  float xs[8] = {xa.x,xa.y,xa.z,xa.w,xc.x,xc.y,xc.z,xc.w};
  f32x4 e4; e4[0]=0.f; e4[1]=0.f; e4[2]=0.f; e4[3]=0.f;
  f32x4 r4 = e4;
  #pragma unroll
  for (int j=0;j<8;++j){
    e4 += valr[j] * xs[j];
    r4 += varr[j] * xs[j];
  }
  #pragma unroll
  for (int m=1;m<16;m<<=1){
    #pragma unroll
    for (int c=0;c<4;++c){
      e4[c] += __shfl_xor(e4[c], m);
      r4[c] += __shfl_xor(r4[c], m);
    }
  }
  if (ql == 0){
    f32x4 es = e4 * LOG2E, rs = r4 * LOG2E;   // pre-scale for exp2 weights
    *(f32x4*)(el + n*4) = es;
    *(f32x4*)(er + n*4) = rs;
  }
}

// ---- bucketed CSR build (fixed-capacity staging; no count pass) ----
__global__ void k_bucket(const int* __restrict__ src, const int* __restrict__ dst,
                         int* __restrict__ bcur, int* __restrict__ staged){
  int e = blockIdx.x*blockDim.x + threadIdx.x;
  if (e < N_EDGES){
    int d = dst[e];
    int b = d >> 7;
    int pos = atomicAdd(&bcur[b*16], 1);
    staged[pos] = (src[e] << 7) | (d & (NPB-1));
  }
}
__global__ __launch_bounds__(1024) void k_bscan(const int* __restrict__ bcur,
    int* __restrict__ bbase){
  __shared__ int lds[1024];
  int t = threadIdx.x;
  int v = (t < NB) ? (bcur[t*16] - t*CAP) : 0;
  lds[t] = v; __syncthreads();
  for (int off=1; off<1024; off<<=1){
    int u = (t>=off)? lds[t-off] : 0;
    __syncthreads();
    lds[t] += u;
    __syncthreads();
  }
  if (t < NB) bbase[t] = lds[t] - v;   // exclusive prefix
  if (t == 0) bbase[NB] = N_EDGES;
}
__global__ __launch_bounds__(256) void k_binsort(const int* __restrict__ staged,
    const int* __restrict__ bcur, const int* __restrict__ bbase,
    int* __restrict__ csr_src, int* __restrict__ indptr){
  __shared__ int hist[NPB];
  __shared__ int scan[NPB];
  __shared__ int lcur[NPB];
  const int b = blockIdx.x, t = threadIdx.x;
  const int st0 = b*CAP;
  const int cnt = bcur[b*16] - st0;
  const int obase = bbase[b];
  if (t < NPB) hist[t] = 0;
  __syncthreads();
  for (int i = t; i < cnt; i += 256)
    atomicAdd(&hist[staged[st0 + i] & (NPB-1)], 1);
  __syncthreads();
  int v = (t < NPB) ? hist[t] : 0;
  if (t < NPB) scan[t] = v;
  __syncthreads();
  for (int off=1; off<NPB; off<<=1){
    int u = (t < NPB && t >= off) ? scan[t-off] : 0;
    __syncthreads();
    if (t < NPB) scan[t] += u;
    __syncthreads();
  }
  const int node0 = b * NPB;
  if (t < NPB){
    int ex = obase + scan[t] - v;    // global exclusive offset for node0+t
    lcur[t] = ex;
    if (node0 + t < N_NODES) indptr[node0 + t] = ex;
  }
  if (b == NB-1 && t == 0) indptr[N_NODES] = N_EDGES;
  __syncthreads();
  for (int i = t; i < cnt; i += 256){
    int pv = staged[st0 + i];
    int pos = atomicAdd(&lcur[pv & (NPB-1)], 1);
    csr_src[pos] = pv >> 7;
  }
}

// ---- layer-1 aggregate over INPUT x (linearity: GEMM deferred to mmpost) ----
// quarter-wave per edge (16 lanes x 16B = 256B bf16 row); 16 edges in flight.
// Per edge: 4 per-head weights into acc[4][8dims]. s_agg bf16 + ssum out.
__global__ __launch_bounds__(256) void k_agg1(const unsigned short* __restrict__ xb,
    const float* __restrict__ el, const float* __restrict__ er,
    const int* __restrict__ indptr, const int* __restrict__ csr_src,
    unsigned short* __restrict__ sagg, float* __restrict__ ssumA){
  int wave = threadIdx.x >> 6, lane = threadIdx.x & 63;
  int n = blockIdx.x*4 + wave;
  if (n >= N_NODES) return;
  int p0 = indptr[n], p1 = indptr[n+1];
  const int q = lane >> 4, ql = lane & 15;
  f32x4 er4 = *(const f32x4*)(er + n*4);
  f32x4 ss; ss[0]=0.f; ss[1]=0.f; ss[2]=0.f; ss[3]=0.f;
  f32x2 acc[4][4];
  #pragma unroll
  for (int h=0;h<4;++h)
    #pragma unroll
    for (int j=0;j<4;++j){ acc[h][j][0]=0.f; acc[h][j][1]=0.f; }
  int e = p0;
  for (; e + 15 < p1; e += 16){
    int s0 = csr_src[e + 0  + q];
    int s1 = csr_src[e + 4  + q];
    int s2 = csr_src[e + 8  + q];
    int s3 = csr_src[e + 12 + q];
    uint4 q0 = *(const uint4*)(xb + (size_t)s0*128 + ql*8);
    uint4 q1 = *(const uint4*)(xb + (size_t)s1*128 + ql*8);
    uint4 q2 = *(const uint4*)(xb + (size_t)s2*128 + ql*8);
    uint4 q3 = *(const uint4*)(xb + (size_t)s3*128 + ql*8);
    f32x4 e0 = *(const f32x4*)(el + s0*4);
    f32x4 e1 = *(const f32x4*)(el + s1*4);
    f32x4 e2 = *(const f32x4*)(el + s2*4);
    f32x4 e3 = *(const f32x4*)(el + s3*4);
    f32x4 w0 = wexp4(e0 + er4);
    f32x4 w1 = wexp4(e1 + er4);
    f32x4 w2 = wexp4(e2 + er4);
    f32x4 w3 = wexp4(e3 + er4);
    ss += (w0 + w1) + (w2 + w3);
    fma_x8(acc, q0, w0);
    fma_x8(acc, q1, w1);
    fma_x8(acc, q2, w2);
    fma_x8(acc, q3, w3);
  }
  for (; e < p1; e += 4){
    int idx = e + q;
    bool ok = idx < p1;
    int s = csr_src[ok ? idx : e];
    uint4 qq = *(const uint4*)(xb + (size_t)s*128 + ql*8);
    f32x4 ee = *(const f32x4*)(el + s*4);
    f32x4 w = wexp4(ee + er4);
    if (!ok){ w[0]=0.f; w[1]=0.f; w[2]=0.f; w[3]=0.f; }
    ss += w;
    fma_x8(acc, qq, w);
  }
  // combine the 4 quarters (disjoint edge subsets, same dim mapping)
  #pragma unroll
  for (int m=16;m<64;m<<=1){
    #pragma unroll
    for (int c=0;c<4;++c) ss[c] += __shfl_xor(ss[c], m);
    #pragma unroll
    for (int h=0;h<4;++h)
      #pragma unroll
      for (int j=0;j<4;++j){
        acc[h][j][0] += __shfl_xor(acc[h][j][0], m);
        acc[h][j][1] += __shfl_xor(acc[h][j][1], m);
      }
  }
  if (q == 0){
    unsigned short* op = sagg + (size_t)n*512 + ql*8;
    #pragma unroll
    for (int h=0;h<4;++h){
      uint4 o;
      o.x = packbf(acc[h][0][0], acc[h][0][1]);
      o.y = packbf(acc[h][1][0], acc[h][1][1]);
      o.z = packbf(acc[h][2][0], acc[h][2][1]);
      o.w = packbf(acc[h][3][0], acc[h][3][1]);
      *(uint4*)(op + h*128) = o;
    }
    if (ql == 0) *(f32x4*)(ssumA + n*4) = ss;
  }
}

// ---- mmpost: h1 = ELU((s_agg . W1)/ssum), IN-PLACE over s_agg ----
// block (mtile, head): reads exactly the 128x128 tile it overwrites.
__global__ __launch_bounds__(256) void k_mmpost(unsigned short* __restrict__ sagg,
    const unsigned short* __restrict__ Bt, const float* __restrict__ ssumA, int M){
  __shared__ unsigned short sm[18432];          // As 128x72 | Bs 128x72
  unsigned short* As = sm;
  unsigned short* Bs = sm + 9216;
  const int t = threadIdx.x;
  const int w = t >> 6, l = t & 63;
  const int quad = l >> 4, l16 = l & 15;
  const int m0 = blockIdx.x * 128;
  const int h = blockIdx.y;
  const int moff = (w & 1) * 64, noff = (w >> 1) * 64;
  f32x4 acc[4][4];
  #pragma unroll
  for (int i=0;i<4;++i)
    #pragma unroll
    for (int j=0;j<4;++j){ acc[i][j][0]=0.f; acc[i][j][1]=0.f; acc[i][j][2]=0.f; acc[i][j][3]=0.f; }
  for (int kb = 0; kb < 2; ++kb){
    const int K0 = kb * 64;
    #pragma unroll
    for (int i=0;i<4;++i){              // A: s_agg head-slice, 128x64 bf16
      int idx = t + i*256;
      int row = idx >> 3, c8 = (idx & 7) * 8;
      uint4 v; v.x=0u; v.y=0u; v.z=0u; v.w=0u;
      if (m0 + row < M)
        v = *(const uint4*)(sagg + (size_t)(m0+row)*512 + h*128 + K0 + c8);
      *(uint4*)(As + row*72 + c8) = v;
    }
    #pragma unroll
    for (int i=0;i<4;++i){              // B: W1t rows h*128..+128
      int idx = t + i*256;
      int row = idx >> 3, c8 = (idx & 7) * 8;
      *(uint4*)(Bs + row*72 + c8) =
        *(const uint4*)(Bt + (size_t)(h*128 + row)*128 + K0 + c8);
    }
    __syncthreads();
    #pragma unroll
    for (int ks = 0; ks < 2; ++ks){
      short8 af[4], bfr[4];
      #pragma unroll
      for (int mi=0; mi<4; ++mi)
        af[mi] = *(const short8*)(As + (moff + mi*16 + l16)*72 + ks*32 + quad*8);
      #pragma unroll
      for (int ni=0; ni<4; ++ni)
        bfr[ni] = *(const short8*)(Bs + (noff + ni*16 + l16)*72 + ks*32 + quad*8);
      #pragma unroll
      for (int mi=0; mi<4; ++mi)
        #pragma unroll
        for (int ni=0; ni<4; ++ni)
          acc[mi][ni] = __builtin_amdgcn_mfma_f32_16x16x32_bf16(af[mi], bfr[ni], acc[mi][ni], 0,0,0);
    }
    __syncthreads();
  }
  // epilogue: divide by ssum, ELU, bf16, coalesced in-place store
  float invr[4][4];
  #pragma unroll
  for (int mi=0; mi<4; ++mi)
    #pragma unroll
    for (int r=0;r<4;++r){
      int gr = m0 + moff + mi*16 + quad*4 + r;
      float s = (gr < M) ? ssumA[gr*4 + h] : 0.f;
      invr[mi][r] = s > 0.f ? 1.f/s : 0.f;
    }
  unsigned short* Cs = sm;                       // 128x136 bf16 (34.8 KB)
  #pragma unroll
  for (int mi=0; mi<4; ++mi)
    #pragma unroll
    for (int ni=0; ni<4; ++ni){
      int col = noff + ni*16 + l16;
      int rb  = moff + mi*16 + quad*4;
      #pragma unroll
      for (int r=0;r<4;++r){
        float v = acc[mi][ni][r] * invr[mi][r];
        v = v > 0.f ? v : __expf(v) - 1.f;       // fused ELU
        Cs[(rb+r)*136 + col] = f2bf(v);
      }
    }
  __syncthreads();
  #pragma unroll
  for (int i=0;i<8;++i){
    int e = t + i*256;
    int row = e >> 4, c8 = (e & 15) * 8;
    if (m0 + row < M)
      *(uint4*)(sagg + (size_t)(m0+row)*512 + h*128 + c8) =
        *(const uint4*)(Cs + row*136 + c8);
  }
}

// ---- GEMM2 (MFMA) + fused layer-2 scores ----
__global__ __launch_bounds__(256) void k_mm2(const unsigned short* __restrict__ A,
    const unsigned short* __restrict__ Bt,
    unsigned short* __restrict__ C, int M,
    const float* __restrict__ al, const float* __restrict__ ar,
    float* __restrict__ el, float* __restrict__ er){
  __shared__ unsigned short sm[13824];          // As 128x72 | Bs 64x72 (27.6 KB)
  unsigned short* As = sm;
  unsigned short* Bs = sm + 9216;
  const int t = threadIdx.x;
  const int w = t >> 6, l = t & 63;
  const int quad = l >> 4, l16 = l & 15;
  const int m0 = blockIdx.x * 128;
  const int moff = w * 32;
  f32x4 acc[2][4];
  #pragma unroll
  for (int i=0;i<2;++i)
    #pragma unroll
    for (int j=0;j<4;++j){ acc[i][j][0]=0.f; acc[i][j][1]=0.f; acc[i][j][2]=0.f; acc[i][j][3]=0.f; }
  for (int kb = 0; kb < 8; ++kb){
    const int K0 = kb * 64;
    #pragma unroll
    for (int i=0;i<4;++i){
      int idx = t + i*256;
      int row = idx >> 3, c8 = (idx & 7) * 8;
      uint4 v; v.x=0u; v.y=0u; v.z=0u; v.w=0u;
      if (m0 + row < M) v = *(const uint4*)(A + (size_t)(m0+row)*512 + K0 + c8);
      *(uint4*)(As + row*72 + c8) = v;
    }
    #pragma unroll
    for (int i=0;i<2;++i){
      int idx = t + i*256;
      int row = idx >> 3, c8 = (idx & 7) * 8;
      *(uint4*)(Bs + row*72 + c8) = *(const uint4*)(Bt + (size_t)row*512 + K0 + c8);
    }
    __syncthreads();
    #pragma unroll
    for (int ks = 0; ks < 2; ++ks){
      short8 af[2], bfr[4];
      #pragma unroll
      for (int mi=0; mi<2; ++mi)
        af[mi] = *(const short8*)(As + (moff + mi*16 + l16)*72 + ks*32 + quad*8);
      #pragma unroll
      for (int ni=0; ni<4; ++ni)
        bfr[ni] = *(const short8*)(Bs + (ni*16 + l16)*72 + ks*32 + quad*8);
      #pragma unroll
      for (int mi=0; mi<2; ++mi)
        #pragma unroll
        for (int ni=0; ni<4; ++ni)
          acc[mi][ni] = __builtin_amdgcn_mfma_f32_16x16x32_bf16(af[mi], bfr[ni], acc[mi][ni], 0,0,0);
    }
    __syncthreads();
  }
  unsigned short* Cs = sm;                       // 128x72 bf16
  #pragma unroll
  for (int mi=0; mi<2; ++mi)
    #pragma unroll
    for (int ni=0; ni<4; ++ni){
      int col = ni*16 + l16;
      int rb  = moff + mi*16 + quad*4;
      #pragma unroll
      for (int r=0;r<4;++r) Cs[(rb+r)*72 + col] = f2bf(acc[mi][ni][r]);
    }
  __syncthreads();
  #pragma unroll
  for (int i=0;i<4;++i){
    int e = t + i*256;
    int row = e >> 3, c8 = (e & 7) * 8;
    if (m0 + row < M)
      *(uint4*)(C + (size_t)(m0+row)*64 + c8) = *(const uint4*)(Cs + row*72 + c8);
  }
  // fused scores: thread pair covers one row (32 cols each)
  {
    int row = t >> 1, half = t & 1;
    const float* alp = al + half*32;
    const float* arp = ar + half*32;
    const unsigned short* cp = Cs + row*72 + half*32;
    float se = 0.f, sr = 0.f;
    #pragma unroll
    for (int i=0;i<4;++i){
      uint4 q = *(const uint4*)(cp + i*8);
      float4 a0 = *(const float4*)(alp + i*8), a1 = *(const float4*)(alp + i*8 + 4);
      float4 r0 = *(const float4*)(arp + i*8), r1 = *(const float4*)(arp + i*8 + 4);
      se += bflo(q.x)*a0.x + bfhi(q.x)*a0.y + bflo(q.y)*a0.z + bfhi(q.y)*a0.w
          + bflo(q.z)*a1.x + bfhi(q.z)*a1.y + bflo(q.w)*a1.z + bfhi(q.w)*a1.w;
      sr += bflo(q.x)*r0.x + bfhi(q.x)*r0.y + bflo(q.y)*r0.z + bfhi(q.y)*r0.w
          + bflo(q.z)*r1.x + bfhi(q.z)*r1.y + bflo(q.w)*r1.z + bfhi(q.w)*r1.w;
    }
    se += __shfl_xor(se, 1); sr += __shfl_xor(sr, 1);
    if (half == 0 && m0 + row < M){
      el[m0+row] = se * LOG2E;   // pre-scale for exp2 weights
      er[m0+row] = sr * LOG2E;
    }
  }
}

// ---- layer-2 aggregate: eighth-wave per edge, 2-edge unroll ----
__global__ __launch_bounds__(256) void k_agg2(const unsigned short* __restrict__ feat,
    const float* __restrict__ el, const float* __restrict__ er,
    const int* __restrict__ indptr, const int* __restrict__ csr_src,
    float* __restrict__ out){
  int wave = threadIdx.x >> 6, lane = threadIdx.x & 63;
  int n = blockIdx.x*4 + wave;
  if (n >= N_NODES) return;
  int p0 = indptr[n], p1 = indptr[n+1];
  float ern = er[n];
  int g = lane >> 3, ql = lane & 7;
  float s = 0.f;
  f32x2 acc[4];
  #pragma unroll
  for (int i=0;i<4;++i){ acc[i][0]=0.f; acc[i][1]=0.f; }
  int e = p0 + g;
  for (; e + 8 < p1; e += 16){
    int sa = csr_src[e], sb = csr_src[e+8];
    uint4 va = *(const uint4*)(feat + (size_t)sa*64 + ql*8);
    uint4 vb = *(const uint4*)(feat + (size_t)sb*64 + ql*8);
    float wa = wexp(el[sa] + ern);
    float wb = wexp(el[sb] + ern);
    s += wa + wb;
    f32x2 Wa; Wa[0]=wa; Wa[1]=wa;
    f32x2 Wb; Wb[0]=wb; Wb[1]=wb;
    f32x2 a;
    a[0]=bflo(va.x); a[1]=bfhi(va.x); pk_fma(acc[0], a, Wa);
    a[0]=bflo(va.y); a[1]=bfhi(va.y); pk_fma(acc[1], a, Wa);
    a[0]=bflo(va.z); a[1]=bfhi(va.z); pk_fma(acc[2], a, Wa);
    a[0]=bflo(va.w); a[1]=bfhi(va.w); pk_fma(acc[3], a, Wa);
    a[0]=bflo(vb.x); a[1]=bfhi(vb.x); pk_fma(acc[0], a, Wb);
    a[0]=bflo(vb.y); a[1]=bfhi(vb.y); pk_fma(acc[1], a, Wb);
    a[0]=bflo(vb.z); a[1]=bfhi(vb.z); pk_fma(acc[2], a, Wb);
    a[0]=bflo(vb.w); a[1]=bfhi(vb.w); pk_fma(acc[3], a, Wb);
  }
  for (; e < p1; e += 8){
    int si = csr_src[e];
    float w = wexp(el[si] + ern);
    uint4 v = *(const uint4*)(feat + (size_t)si*64 + ql*8);
    s += w;
    f32x2 W; W[0]=w; W[1]=w;
    f32x2 a;
    a[0]=bflo(v.x); a[1]=bfhi(v.x); pk_fma(acc[0], a, W);
    a[0]=bflo(v.y); a[1]=bfhi(v.y); pk_fma(acc[1], a, W);
    a[0]=bflo(v.z); a[1]=bfhi(v.z); pk_fma(acc[2], a, W);
    a[0]=bflo(v.w); a[1]=bfhi(v.w); pk_fma(acc[3], a, W);
  }
  #pragma unroll
  for (int m=8;m<64;m<<=1){
    s += __shfl_xor(s,m);
    #pragma unroll
    for (int i=0;i<4;++i){
      acc[i][0] += __shfl_xor(acc[i][0],m);
      acc[i][1] += __shfl_xor(acc[i][1],m);
    }
  }
  float inv = s > 0.f ? 1.f/s : 0.f;
  if (g == 0){
    float* op = out + (size_t)n*64 + ql*8;
    *(float4*)op     = make_float4(acc[0][0]*inv, acc[0][1]*inv, acc[1][0]*inv, acc[1][1]*inv);
    *(float4*)(op+4) = make_float4(acc[2][0]*inv, acc[2][1]*inv, acc[3][0]*inv, acc[3][1]*inv);
  }
}

extern "C" void kernel_launch(void* const* d_in, const int* in_sizes, int n_in,
                              void* d_out, int out_size, void* d_ws, size_t ws_size,
                              hipStream_t stream){
  const float* x   = (const float*)d_in[0];
  const float* W1  = (const float*)d_in[1];
  const float* al1 = (const float*)d_in[2];
  const float* ar1 = (const float*)d_in[3];
  const float* W2  = (const float*)d_in[4];
  const float* al2 = (const float*)d_in[5];
  const float* ar2 = (const float*)d_in[6];
  const int* src   = (const int*)d_in[7];
  const int* dst   = (const int*)d_in[8];
  float* out = (float*)d_out;

  char* ws = (char*)d_ws;
  size_t off = 0;
  auto alloc = [&](size_t bytes)->char*{
    char* p = ws + off; off += (bytes + 255) & ~(size_t)255; return p;
  };
  unsigned short* xbuf = (unsigned short*)alloc((size_t)N_NODES*128*2);   // 25.6 MB bf16 x
  unsigned short* sagg = (unsigned short*)alloc((size_t)N_NODES*512*2);   // 102.4 MB; becomes h1 in-place
  float* ssumA = (float*)alloc((size_t)N_NODES*4*4);                      // 1.6 MB
  unsigned short* W1t = (unsigned short*)alloc(512*128*2);
  unsigned short* W2t = (unsigned short*)alloc(64*512*2);
  float* val  = (float*)alloc(512*4);
  float* var  = (float*)alloc(512*4);
  float* el1 = (float*)alloc((size_t)N_NODES*4*4);
  float* er1 = (float*)alloc((size_t)N_NODES*4*4);
  float* el2 = el1;                           // alias: el1 dead after k_agg1
  float* er2 = er1;
  int* bcur    = (int*)alloc((size_t)NB*16*4);        // padded: 1 counter / 64B
  int* bbase   = (int*)alloc((size_t)(NB+1)*4);
  int* indptr  = (int*)alloc((size_t)(N_NODES+1)*4);
  int* staged  = (int*)alloc((size_t)NB*CAP*4);                           // 14.4 MB
  int* csr_src = (int*)alloc((size_t)N_EDGES*4);                          // 12.8 MB
  unsigned short* feat2b = (unsigned short*)staged;  // alias: staged dead after binsort
  // total ~161 MB (< proven 222 MB footprint)

  dim3 b256(256);
  // prep: W1t, W2t, bucket cursors, score vectors (one launch)
  k_prep<<<dim3(392), b256, 0, stream>>>(W1, W2, al1, ar1, W1t, W2t, bcur, val, var);
  // x -> bf16 + layer-1 scores (GEMV via precomputed val/var)
  k_xcvt<<<dim3(6250), b256, 0, stream>>>(x, val, var, xbuf, el1, er1);
  // bucketed dst-CSR: scatter into fixed-capacity buckets -> scan -> per-bucket sort
  k_bucket<<<dim3((N_EDGES+255)/256), b256, 0, stream>>>(src, dst, bcur, staged);
  k_bscan<<<dim3(1), dim3(1024), 0, stream>>>(bcur, bbase);
  k_binsort<<<dim3(NB), b256, 0, stream>>>(staged, bcur, bbase, csr_src, indptr);
  // layer-1 aggregate over x (256B/edge gather; GEMM deferred)
  k_agg1<<<dim3(25000), b256, 0, stream>>>(xbuf, el1, er1, indptr, csr_src, sagg, ssumA);
  // deferred projection + softmax-div + ELU, in-place: sagg -> h1
  k_mmpost<<<dim3(782, 4), b256, 0, stream>>>(sagg, W1t, ssumA, N_NODES);
  // layer 2 (MFMA) + fused scores
  k_mm2<<<dim3(782), b256, 0, stream>>>(sagg, W2t, feat2b, N_NODES, al2, ar2, el2, er2);
  k_agg2<<<dim3(25000), b256, 0, stream>>>(feat2b, el2, er2, indptr, csr_src, out);
}